// Round 6
// baseline (331.217 us; speedup 1.0000x reference)
//
#include <hip/hip_runtime.h>
#include <hip/hip_bf16.h>

// BahdanauAttention on MI355X (gfx950). ALL float I/O is fp32.
// Internal compute uses bf16 MFMA (no fp32 MFMA on CDNA4).
// Pipeline (5 launches) — R21: K2 = TQ=8 x h-split (B-byte halving):
//  K0: cast fp32->bf16 for query/enc/W_s/W_h/W_out into ws
//  K1: EA = exp(2*(query @ W_s^T)) [2048x512], EBT = exp(2*(enc @ Wh^T))^T
//      [512x2048]  (exp-product form: tanh(a+b)=1-2/(1+e^2a e^2b))
//      gload_lds(16B) staging, XOR-swizzled source, linear LDS (R16).
//  K2: partial energies, h split across 2 blocks (hf: 256 h each), TQ=8
//      t-rows/block. Block=(b, j, hf, tq5), wave=32-h slice, lane=2 s.
//      Grid 1024, LDS 42.6 KB -> 3 blocks/CU (24 waves). B-stream (EBT
//      re-reads) = ~98 MB vs v9's 196 MB — K2 is cache-BW-bound (R20).
//  K3: softmax(E0+E1, len) -> LDS bf16 weights; ctx = W @ enc [MFMA, fused]
//  K4: out = tanh([ctx|query] @ W_out^T)  [32x64 LDS-tiled MFMA, concat-K]
// R16 lesson: gload_lds staging in K1/K4 = -1.6us (TLP already hid most).
// R17 lesson: v_pk_fma_f32 adds NO fp32 throughput on CDNA4.
// R18 lesson: cg::grid.sync() costs ~60us/sync on MI355X — never fuse
// us-scale phases behind grid-wide barriers on this chip.
// R19 lesson: K2 dominates (52us); TQ=8 without h-split halved the grid
// and tanked occupancy (31%).
// R20 lesson: K2 at FULL occupancy is still ~42us (VALU floor 8.5us):
// bound by EBT re-read bandwidth from L2/L3 (~4.7 TB/s effective; 4MB EBT
// thrashes the per-XCD 4MB L2). B-bytes scale 1/TQ -> raise TQ while
// keeping 3+ blocks/CU via the h-split.
// d_ws is 256 MiB; harness 0xAA fill (~43.5 us) is a fixed serialized cost.

typedef __attribute__((ext_vector_type(8))) short bf16x8;
typedef __attribute__((ext_vector_type(4))) float floatx4;

#define C2LOG2E 2.8853900817779268f   // 2*log2(e)
#define LOG2E   1.4426950408889634f
#define NEGBIG  -1e30f

__device__ __forceinline__ float fexp2(float x) { return __builtin_amdgcn_exp2f(x); }
__device__ __forceinline__ float frcp(float x)  { return __builtin_amdgcn_rcpf(x); }
__device__ __forceinline__ float ftanh(float x) {
    return 1.0f - 2.0f * frcp(1.0f + fexp2(C2LOG2E * x));
}
__device__ __forceinline__ float fexp2x(float x) {   // e^{2x}
    return fexp2(C2LOG2E * x);
}

__device__ __forceinline__ unsigned int f2bf_bits(float f) {
    unsigned int u = __float_as_uint(f);
    return (u + 0x7fffu + ((u >> 16) & 1u)) >> 16;   // RNE (inputs finite)
}

// async 16B global->LDS (wave-cooperative: lane i writes ldsbase + i*16)
typedef const __attribute__((address_space(1))) unsigned int* gas_u32p;
typedef __attribute__((address_space(3))) unsigned int* las_u32p;
__device__ __forceinline__ void gload16(const void* g, void* l) {
    __builtin_amdgcn_global_load_lds((gas_u32p)g, (las_u32p)l, 16, 0, 0);
}

// ---- K0: cast fp32 -> bf16. 3072 blocks x 256 thr ---------------------------
__global__ __launch_bounds__(256) void cast_all_bf16(
    const float* __restrict__ q,  const float* __restrict__ e,
    const float* __restrict__ Ws, const float* __restrict__ Wh,
    const float* __restrict__ Wo,
    unsigned short* __restrict__ qb,  unsigned short* __restrict__ eb,
    unsigned short* __restrict__ Wsb, unsigned short* __restrict__ Whb,
    unsigned short* __restrict__ Wob)
{
    int blk = blockIdx.x;
    const float* src; unsigned short* dst; int base;
    if      (blk < 1024) { src = q;  dst = qb;  base = blk; }
    else if (blk < 2048) { src = e;  dst = eb;  base = blk - 1024; }
    else if (blk < 2304) { src = Ws; dst = Wsb; base = blk - 2048; }
    else if (blk < 2560) { src = Wh; dst = Whb; base = blk - 2304; }
    else                 { src = Wo; dst = Wob; base = blk - 2560; }
    size_t i = (size_t)base * 1024 + threadIdx.x * 4;
    float4 f = *(const float4*)(src + i);
    ushort4 o;
    o.x = (unsigned short)f2bf_bits(f.x);
    o.y = (unsigned short)f2bf_bits(f.y);
    o.z = (unsigned short)f2bf_bits(f.z);
    o.w = (unsigned short)f2bf_bits(f.w);
    *(ushort4*)(dst + i) = o;
}

// ---- K1: 32x64-tile gload_lds GEMM, dual-shape: C = exp(2*(X @ W^T)) --------
// Part A (blk<512):  X=qb[2048x512],  W=Wsb[512x512],  C=EA  [2048x512]
// Part B (blk>=512): X=Whb[512x512],  W=eb[2048x512],  C=EBT [512x2048]
__global__ __launch_bounds__(256) void gemm32x64_exp_dual(
    const unsigned short* __restrict__ Xa, const unsigned short* __restrict__ Wa,
    float* __restrict__ Ca,
    const unsigned short* __restrict__ Xb, const unsigned short* __restrict__ Wb_,
    float* __restrict__ Cb)
{
    __shared__ unsigned short sA[32 * 64];   // 4 KB, linear (swizzled content)
    __shared__ unsigned short sB[64 * 64];   // 8 KB
    const int K = 512;
    int blk = blockIdx.x;
    const unsigned short* X; const unsigned short* W; float* C;
    int mt, nt, N;
    if (blk < 512) { X = Xa; W = Wa; C = Ca; N = 512;  mt = blk >> 3; nt = blk & 7; }
    else { blk -= 512; X = Xb; W = Wb_; C = Cb; N = 2048; mt = blk >> 5; nt = blk & 31; }
    int row0 = mt * 32, col0 = nt * 64;
    int tid = threadIdx.x, lane = tid & 63, w = tid >> 6;
    int mw = (w & 1) * 16, nw = (w >> 1) * 32;
    int r = lane & 15;

    // staging: wave w stages A rows 8w..8w+7 (1 call) and B rows 16w..16w+15
    // (2 calls). lane l -> row +(l>>3), col chunk ((l&7)^(l>>3))*8 shorts.
    int lr  = lane >> 3;
    int csw = ((lane & 7) ^ lr) << 3;        // swizzled col (shorts)
    const unsigned short* gA  = X + (size_t)(row0 + 8 * w + lr) * K + csw;
    const unsigned short* gB0 = W + (size_t)(col0 + 16 * w + lr) * K + csw;
    const unsigned short* gB1 = W + (size_t)(col0 + 16 * w + 8 + lr) * K + csw;
    unsigned short* lA  = &sA[w * 512];
    unsigned short* lB0 = &sB[w * 1024];
    unsigned short* lB1 = &sB[w * 1024 + 512];

    // read offsets (bytes), loop-invariant
    int xr = (r & 7) << 4;
    int cq = (lane >> 4) << 4;               // 0,16,32,48
    const char* cA = (const char*)sA;
    const char* cB = (const char*)sB;
    int a0 = (mw + r) * 128 + (cq ^ xr);
    int a1 = (mw + r) * 128 + ((cq + 64) ^ xr);
    int b0 = (nw + r) * 128 + (cq ^ xr);
    int b1 = (nw + r) * 128 + ((cq + 64) ^ xr);

    floatx4 acc0 = {0,0,0,0}, acc1 = {0,0,0,0};
    gload16(gA, lA); gload16(gB0, lB0); gload16(gB1, lB1);   // stage kb=0

    for (int kb = 0; kb < 8; ++kb) {
        __syncthreads();                     // drains vmcnt -> tile ready
        bf16x8 af0 = *(const bf16x8*)(cA + a0);
        bf16x8 af1 = *(const bf16x8*)(cA + a1);
        bf16x8 b00 = *(const bf16x8*)(cB + b0);
        bf16x8 b10 = *(const bf16x8*)(cB + b0 + 2048);
        bf16x8 b01 = *(const bf16x8*)(cB + b1);
        bf16x8 b11 = *(const bf16x8*)(cB + b1 + 2048);
        acc0 = __builtin_amdgcn_mfma_f32_16x16x32_bf16(af0, b00, acc0, 0, 0, 0);
        acc1 = __builtin_amdgcn_mfma_f32_16x16x32_bf16(af0, b10, acc1, 0, 0, 0);
        acc0 = __builtin_amdgcn_mfma_f32_16x16x32_bf16(af1, b01, acc0, 0, 0, 0);
        acc1 = __builtin_amdgcn_mfma_f32_16x16x32_bf16(af1, b11, acc1, 0, 0, 0);
        if (kb < 7) {
            __syncthreads();                 // all waves done reading
            gA += 64; gB0 += 64; gB1 += 64;
            gload16(gA, lA); gload16(gB0, lB0); gload16(gB1, lB1);
        }
    }
    int rq = (lane >> 4) * 4;
    float* cp = C + (size_t)(row0 + mw + rq) * N + col0 + nw + r;
#pragma unroll
    for (int i = 0; i < 4; ++i) {
        cp[(size_t)i * N]      = fexp2x(acc0[i]);
        cp[(size_t)i * N + 16] = fexp2x(acc1[i]);
    }
}

// ---- K2: partial energies. 1024 blocks = (b<<7)|(j<<6)|(hf<<5)|tq, 512 thr --
// Block: batch b, t-rows tq*8..+7, s-group j (128 s), h-half hf (256 h).
// Early exit: j*128>=len. Wave w: 32-h slice within the half; lane: 2 s.
// Epart(t,s) = sum_{h in half} wn_h/(1+EA*EB), wn=-2v. E = E0+E1 (in K3).
// A/v LDS broadcast, B 1-deep pipelined; doU1 skips masked upper 64-s half.
// TQ=8: EBT bytes/dispatch ~98 MB (half of R20's v9) — the binding resource.
// LDS 42.6 KB -> 3 blocks/CU; launch_bounds(512,6) caps VGPR for 24 waves/CU.
#define TQ8 8
__global__ __launch_bounds__(512, 6) void energies_v10(
    const float* __restrict__ EA,          // [2048][512] e^{2*Ws_q}
    const float* __restrict__ EBT,         // [512][2048] e^{2*Wh_e} transposed
    const float* __restrict__ Vv,          // fp32 512
    const int* __restrict__ Len,
    float* __restrict__ E0,                // fp32 [2048][256] partial (h<256)
    float* __restrict__ E1)                // fp32 [2048][256] partial (h>=256)
{
    __shared__ float sA[TQ8][260];         // 8.3 KB (h-half of EA rows)
    __shared__ float sWn[256];             // 1 KB  (-2*v, h-half)
    __shared__ float sRed[8][TQ8][130];    // 33.3 KB

    int tid  = threadIdx.x;
    int lane = tid & 63;
    int w    = tid >> 6;
    int blk  = blockIdx.x;
    int b    = blk >> 7;
    int j    = (blk >> 6) & 1;
    int hf   = (blk >> 5) & 1;
    int tq   = blk & 31;                   // low bits -> XCD balance
    int len  = Len[b];
    if (j * 128 >= len) return;            // block-uniform early exit
    bool doU1 = (j * 128 + 64) < len;      // upper 64-s half needed?
    int row0g = b * 256 + tq * TQ8;

    {   // stage EA rows (8 x 256 fp32, this h-half) and wn
        int t = tid >> 6, c = (tid & 63) * 4;
        *(float4*)&sA[t][c] = *(const float4*)(EA + (size_t)(row0g + t) * 512 + hf * 256 + c);
        if (tid < 256) sWn[tid] = -2.0f * Vv[hf * 256 + tid];
    }
    __syncthreads();

    int h0 = w * 32;                       // local h-slice within the half
    float acc[TQ8][2];
#pragma unroll
    for (int t = 0; t < TQ8; ++t) { acc[t][0] = 0.f; acc[t][1] = 0.f; }
    const float* bt = EBT + (size_t)(hf * 256 + h0) * 2048 + b * 256 + j * 128 + lane;

    // software pipeline: prefetch B for hh=0 (4 h x up-to-2 s-halves)
    float B[8] = {0}, P[8] = {0};
#pragma unroll
    for (int i = 0; i < 4; ++i) B[i] = bt[(size_t)i * 2048];
    if (doU1) {
#pragma unroll
        for (int i = 0; i < 4; ++i) B[i + 4] = bt[(size_t)i * 2048 + 64];
    }
#pragma unroll
    for (int hh = 0; hh < 32; hh += 4) {
        if (hh + 4 < 32) {                 // prefetch next iteration's B
            const float* nb = bt + (size_t)(hh + 4) * 2048;
#pragma unroll
            for (int i = 0; i < 4; ++i) P[i] = nb[(size_t)i * 2048];
            if (doU1) {
#pragma unroll
                for (int i = 0; i < 4; ++i) P[i + 4] = nb[(size_t)i * 2048 + 64];
            }
        }
        float4 w4 = *(const float4*)&sWn[h0 + hh];            // LDS broadcast
#pragma unroll
        for (int t = 0; t < TQ8; ++t) {
            float4 a4 = *(const float4*)&sA[t][h0 + hh];      // LDS broadcast
            {   // u = 0 (always live)
                float d0 = fmaf(a4.x, B[0], 1.0f);
                float d1 = fmaf(a4.y, B[1], 1.0f);
                float d2 = fmaf(a4.z, B[2], 1.0f);
                float d3 = fmaf(a4.w, B[3], 1.0f);
                float num01 = fmaf(w4.x, d1, w4.y * d0);
                float num23 = fmaf(w4.z, d3, w4.w * d2);
                acc[t][0] = fmaf(num01, frcp(d0 * d1), acc[t][0]);
                acc[t][0] = fmaf(num23, frcp(d2 * d3), acc[t][0]);
            }
            if (doU1) {                    // u = 1 (masked off when len small)
                float d0 = fmaf(a4.x, B[4], 1.0f);
                float d1 = fmaf(a4.y, B[5], 1.0f);
                float d2 = fmaf(a4.z, B[6], 1.0f);
                float d3 = fmaf(a4.w, B[7], 1.0f);
                float num01 = fmaf(w4.x, d1, w4.y * d0);
                float num23 = fmaf(w4.z, d3, w4.w * d2);
                acc[t][1] = fmaf(num01, frcp(d0 * d1), acc[t][1]);
                acc[t][1] = fmaf(num23, frcp(d2 * d3), acc[t][1]);
            }
        }
#pragma unroll
        for (int i = 0; i < 8; ++i) B[i] = P[i];
    }

#pragma unroll
    for (int t = 0; t < TQ8; ++t) {
        sRed[w][t][lane]      = acc[t][0];
        sRed[w][t][lane + 64] = acc[t][1];   // 0s when !doU1 (never read by K3)
    }
    __syncthreads();
    {
        int s = tid & 127;
        float* Ep = hf ? E1 : E0;
#pragma unroll
        for (int half = 0; half < 2; ++half) {
            int t = (tid >> 7) + 4 * half;   // 512 thr x 2 passes: 8t x 128s
            float sum = 0.f;
#pragma unroll
            for (int ww = 0; ww < 8; ++ww) sum += sRed[ww][t][s];
            Ep[(size_t)(row0g + t) * 256 + j * 128 + s] = sum;
        }
    }
}

// ---- K3: fused softmax + ctx GEMM. 256 blocks = (tg<<6)|(hq<<3)|b, 512 thr --
__global__ __launch_bounds__(512) void softmax_ctx_fused(
    const float* __restrict__ E0,            // fp32 [2048][256] h<256 partial
    const float* __restrict__ E1,            // fp32 [2048][256] h>=256 partial
    const unsigned short* __restrict__ Eb,   // bf16 8x256x512
    const int* __restrict__ Len,
    unsigned short* __restrict__ Ctx)        // bf16 2048x512
{
    __shared__ unsigned short EncT[64][264];
    __shared__ unsigned short sWb[64][264];
    int tid = threadIdx.x, lane = tid & 63, w = tid >> 6;
    int blk = blockIdx.x;
    int b = blk & 7, hq = (blk >> 3) & 7, tg = blk >> 6;
    int len = Len[b];

    {   // stage + transpose enc tile: thread (s, 32-h half)
        int s = tid >> 1, hg = (tid & 1) * 32;
        const ushort4* src = (const ushort4*)(Eb + (size_t)(b * 256 + s) * 512 + hq * 64 + hg);
#pragma unroll
        for (int k = 0; k < 8; ++k) {
            ushort4 u = src[k];
            EncT[hg + k * 4 + 0][s] = u.x;
            EncT[hg + k * 4 + 1][s] = u.y;
            EncT[hg + k * 4 + 2][s] = u.z;
            EncT[hg + k * 4 + 3][s] = u.w;
        }
    }
    // softmax: wave w owns rows w*8 .. w*8+7 of the 64-row tile
    for (int i = 0; i < 8; ++i) {
        int row = w * 8 + i;
        size_t ro = (size_t)(b * 256 + tg * 64 + row) * 256;
        const float* er0 = E0 + ro;
        const float* er1 = E1 + ro;
        float ev[4];
#pragma unroll
        for (int j = 0; j < 4; ++j) {
            int s = lane + 64 * j;
            ev[j] = (s < len) ? (er0[s] + er1[s]) : NEGBIG;
        }
        float m = fmaxf(fmaxf(ev[0], ev[1]), fmaxf(ev[2], ev[3]));
#pragma unroll
        for (int o = 1; o < 64; o <<= 1) m = fmaxf(m, __shfl_xor(m, o, 64));
        float wv[4], wsum = 0.f;
#pragma unroll
        for (int j = 0; j < 4; ++j) { wv[j] = fexp2((ev[j] - m) * LOG2E); wsum += wv[j]; }
#pragma unroll
        for (int o = 1; o < 64; o <<= 1) wsum += __shfl_xor(wsum, o, 64);
        float inv = frcp(wsum);
#pragma unroll
        for (int j = 0; j < 4; ++j)
            sWb[row][lane + 64 * j] = (unsigned short)f2bf_bits(wv[j] * inv);
    }
    __syncthreads();

    int mt = w & 3, npair = w >> 2;          // wave: 16 t x 32 h (2 n-tiles)
    int t0 = mt * 16;
    int r  = lane & 15, kq = (lane >> 4) * 8;
    int n0 = npair * 32 + r;
    floatx4 acc0 = {0.f,0.f,0.f,0.f}, acc1 = {0.f,0.f,0.f,0.f};
#pragma unroll
    for (int k = 0; k < 8; ++k) {
        bf16x8 a  = *(const bf16x8*)(&sWb[t0 + r][kq + 32 * k]);
        bf16x8 b0 = *(const bf16x8*)(&EncT[n0][kq + 32 * k]);
        bf16x8 b1 = *(const bf16x8*)(&EncT[n0 + 16][kq + 32 * k]);
        acc0 = __builtin_amdgcn_mfma_f32_16x16x32_bf16(a, b0, acc0, 0, 0, 0);
        acc1 = __builtin_amdgcn_mfma_f32_16x16x32_bf16(a, b1, acc1, 0, 0, 0);
    }
    int row0 = (lane >> 4) * 4;
    unsigned short* op = Ctx + (size_t)(b * 256 + tg * 64 + t0 + row0) * 512 + hq * 64 + npair * 32 + r;
#pragma unroll
    for (int i = 0; i < 4; ++i) {
        op[i * 512]      = (unsigned short)f2bf_bits(acc0[i]);
        op[i * 512 + 16] = (unsigned short)f2bf_bits(acc1[i]);
    }
}

// ---- K4: 32x64-tile gload_lds GEMM, concat-K: out = tanh([ctx|q] @ Wout^T) --
__global__ __launch_bounds__(256) void out_gemm32x64_tanh(
    const unsigned short* __restrict__ Ctx, const unsigned short* __restrict__ Q,
    const unsigned short* __restrict__ Wout, float* __restrict__ Out)
{
    __shared__ unsigned short sA[32 * 64];
    __shared__ unsigned short sB[64 * 64];
    const int N = 512, KW = 1024;
    int blk = blockIdx.x;
    int mt = blk >> 3, nt = blk & 7;
    int row0 = mt * 32, col0 = nt * 64;
    int tid = threadIdx.x, lane = tid & 63, w = tid >> 6;
    int mw = (w & 1) * 16, nw = (w >> 1) * 32;
    int r = lane & 15;

    int lr  = lane >> 3;
    int csw = ((lane & 7) ^ lr) << 3;
    const unsigned short* gactx = Ctx  + (size_t)(row0 + 8 * w + lr) * 512 + csw;
    const unsigned short* gaq   = Q    + (size_t)(row0 + 8 * w + lr) * 512 + csw;
    const unsigned short* gB0   = Wout + (size_t)(col0 + 16 * w + lr) * KW + csw;
    const unsigned short* gB1   = Wout + (size_t)(col0 + 16 * w + 8 + lr) * KW + csw;
    unsigned short* lA  = &sA[w * 512];
    unsigned short* lB0 = &sB[w * 1024];
    unsigned short* lB1 = &sB[w * 1024 + 512];

    int xr = (r & 7) << 4;
    int cq = (lane >> 4) << 4;
    const char* cA = (const char*)sA;
    const char* cB = (const char*)sB;
    int a0 = (mw + r) * 128 + (cq ^ xr);
    int a1 = (mw + r) * 128 + ((cq + 64) ^ xr);
    int b0 = (nw + r) * 128 + (cq ^ xr);
    int b1 = (nw + r) * 128 + ((cq + 64) ^ xr);

    floatx4 acc0 = {0,0,0,0}, acc1 = {0,0,0,0};
    gload16(gactx, lA); gload16(gB0, lB0); gload16(gB1, lB1);   // stage kb=0

    for (int kb = 0; kb < 16; ++kb) {
        __syncthreads();
        bf16x8 af0 = *(const bf16x8*)(cA + a0);
        bf16x8 af1 = *(const bf16x8*)(cA + a1);
        bf16x8 b00 = *(const bf16x8*)(cB + b0);
        bf16x8 b10 = *(const bf16x8*)(cB + b0 + 2048);
        bf16x8 b01 = *(const bf16x8*)(cB + b1);
        bf16x8 b11 = *(const bf16x8*)(cB + b1 + 2048);
        acc0 = __builtin_amdgcn_mfma_f32_16x16x32_bf16(af0, b00, acc0, 0, 0, 0);
        acc1 = __builtin_amdgcn_mfma_f32_16x16x32_bf16(af0, b10, acc1, 0, 0, 0);
        acc0 = __builtin_amdgcn_mfma_f32_16x16x32_bf16(af1, b01, acc0, 0, 0, 0);
        acc1 = __builtin_amdgcn_mfma_f32_16x16x32_bf16(af1, b11, acc1, 0, 0, 0);
        if (kb < 15) {
            __syncthreads();
            int kn = kb + 1;
            const unsigned short* ga = (kn < 8 ? gactx : gaq) + (kn & 7) * 64;
            gB0 += 64; gB1 += 64;
            gload16(ga, lA); gload16(gB0, lB0); gload16(gB1, lB1);
        }
    }
    int rq = (lane >> 4) * 4;
    float* op = Out + (size_t)(row0 + mw + rq) * N + col0 + nw + r;
#pragma unroll
    for (int i = 0; i < 4; ++i) {
        op[(size_t)i * N]      = ftanh(acc0[i]);
        op[(size_t)i * N + 16] = ftanh(acc1[i]);
    }
}

extern "C" void kernel_launch(void* const* d_in, const int* in_sizes, int n_in,
                              void* d_out, int out_size, void* d_ws, size_t ws_size,
                              hipStream_t stream)
{
    const float* query = (const float*)d_in[0]; // fp32 8x256x512
    const float* enc   = (const float*)d_in[1]; // fp32 8x256x512
    const int*   len   = (const int*)d_in[2];   // int32 8
    const float* Ws    = (const float*)d_in[3]; // fp32 512x512
    const float* Wh    = (const float*)d_in[4]; // fp32 512x512
    const float* v     = (const float*)d_in[5]; // fp32 512
    const float* Wout  = (const float*)d_in[6]; // fp32 512x1024
    float* out = (float*)d_out;                 // fp32 8x256x512

    // d_ws is 256 MiB; generous non-aliased layout (~22 MB used)
    float* EA   = (float*)d_ws;                                   // 4 MB [2048][512]
    float* EBT  = EA + 2048 * 512;                                // 4 MB [512][2048]
    float* E0   = EBT + 512 * 2048;                               // 2 MB [2048][256]
    float* E1   = E0 + 2048 * 256;                                // 2 MB [2048][256]
    unsigned short* qb  = (unsigned short*)(E1 + 2048 * 256);     // 2 MB
    unsigned short* eb  = qb + 2048 * 512;                        // 2 MB
    unsigned short* Wsb = eb + 2048 * 512;                        // 0.5 MB
    unsigned short* Whb = Wsb + 512 * 512;                        // 0.5 MB
    unsigned short* Wob = Whb + 512 * 512;                        // 1 MB
    unsigned short* ctx = Wob + 512 * 1024;                       // 2 MB

    cast_all_bf16<<<3072, 256, 0, stream>>>(query, enc, Ws, Wh, Wout,
                                            qb, eb, Wsb, Whb, Wob);
    gemm32x64_exp_dual<<<1024, 256, 0, stream>>>(qb, Wsb, EA, Whb, eb, EBT);
    energies_v10<<<1024, 512, 0, stream>>>(EA, EBT, v, len, E0, E1);
    softmax_ctx_fused<<<256, 512, 0, stream>>>(E0, E1, eb, len, ctx);
    out_gemm32x64_tanh<<<512, 256, 0, stream>>>(ctx, qb, Wob, out);
}

// Round 7
// 120.189 us; speedup vs baseline: 2.7558x; 2.7558x over previous
//
#include <hip/hip_runtime.h>
#include <hip/hip_bf16.h>

// BahdanauAttention on MI355X (gfx950). ALL float I/O is fp32.
// Internal compute uses bf16 MFMA (no fp32 MFMA on CDNA4).
// Pipeline (5 launches) — R22: R16 pipeline, K2 with bf16-EBT (half B-bytes):
//  K0: cast fp32->bf16 for query/enc/W_s/W_h/W_out into ws
//  K1: EA = exp(2*(query @ W_s^T)) [2048x512] fp32,
//      EBT = bf16(exp(2*(enc @ Wh^T)))^T [512][2048]  (exp-product form:
//      tanh(a+b)=1-2/(1+e^2a e^2b)). gload_lds(16B) staging, XOR-swizzle.
//  K2: energies E[t][s] = sum_h (-2 v_h)/(1+EA*EB). Block=(b, 4 t, 128-s grp),
//      wave=64-h slice, lane = s-pair (2lane, 2lane+1): one u32 load = 2 bf16
//      s-values -> 4 loads/4-h iter (was 8), half bytes/lines. Unpack = shift/
//      and (2 VALU per u32). A/v fp32 LDS broadcast; B 1-deep pipelined.
//  K3: softmax(E, len) -> LDS bf16 weights; ctx = W @ enc [MFMA, fused]
//  K4: out = tanh([ctx|query] @ W_out^T)  [32x64 LDS-tiled MFMA, concat-K]
// R16 lesson: gload_lds staging in K1/K4 = -1.6us (TLP already hid most).
// R17 lesson: v_pk_fma_f32 adds NO fp32 throughput on CDNA4.
// R18 lesson: cg::grid.sync() ~60us/sync on MI355X — never grid-fuse us-scale
// phases.
// R19 lesson: K2 dominates (~39-52us); big-TQ without occupancy = latency hell.
// R20 lesson: K2 at full occupancy still ~42us — B-stream bound, not VALU
// (VALU floor 14.5us measured).
// R21 lesson: __launch_bounds__(512,6) forced a VGPR cap below natural use ->
// spill-to-scratch: 240MB FETCH + 442MB WRITE per dispatch, 224us. Never buy
// occupancy with forced spill.
// d_ws is 256 MiB; harness 0xAA fill (~43.5 us) is a fixed serialized cost.

typedef __attribute__((ext_vector_type(8))) short bf16x8;
typedef __attribute__((ext_vector_type(4))) float floatx4;

#define C2LOG2E 2.8853900817779268f   // 2*log2(e)
#define LOG2E   1.4426950408889634f
#define NEGBIG  -1e30f
#define TQ 4

__device__ __forceinline__ float fexp2(float x) { return __builtin_amdgcn_exp2f(x); }
__device__ __forceinline__ float frcp(float x)  { return __builtin_amdgcn_rcpf(x); }
__device__ __forceinline__ float ftanh(float x) {
    return 1.0f - 2.0f * frcp(1.0f + fexp2(C2LOG2E * x));
}
__device__ __forceinline__ float fexp2x(float x) {   // e^{2x}
    return fexp2(C2LOG2E * x);
}

__device__ __forceinline__ unsigned int f2bf_bits(float f) {
    unsigned int u = __float_as_uint(f);
    return (u + 0x7fffu + ((u >> 16) & 1u)) >> 16;   // RNE (inputs finite)
}

// async 16B global->LDS (wave-cooperative: lane i writes ldsbase + i*16)
typedef const __attribute__((address_space(1))) unsigned int* gas_u32p;
typedef __attribute__((address_space(3))) unsigned int* las_u32p;
__device__ __forceinline__ void gload16(const void* g, void* l) {
    __builtin_amdgcn_global_load_lds((gas_u32p)g, (las_u32p)l, 16, 0, 0);
}

// ---- K0: cast fp32 -> bf16. 3072 blocks x 256 thr ---------------------------
__global__ __launch_bounds__(256) void cast_all_bf16(
    const float* __restrict__ q,  const float* __restrict__ e,
    const float* __restrict__ Ws, const float* __restrict__ Wh,
    const float* __restrict__ Wo,
    unsigned short* __restrict__ qb,  unsigned short* __restrict__ eb,
    unsigned short* __restrict__ Wsb, unsigned short* __restrict__ Whb,
    unsigned short* __restrict__ Wob)
{
    int blk = blockIdx.x;
    const float* src; unsigned short* dst; int base;
    if      (blk < 1024) { src = q;  dst = qb;  base = blk; }
    else if (blk < 2048) { src = e;  dst = eb;  base = blk - 1024; }
    else if (blk < 2304) { src = Ws; dst = Wsb; base = blk - 2048; }
    else if (blk < 2560) { src = Wh; dst = Whb; base = blk - 2304; }
    else                 { src = Wo; dst = Wob; base = blk - 2560; }
    size_t i = (size_t)base * 1024 + threadIdx.x * 4;
    float4 f = *(const float4*)(src + i);
    ushort4 o;
    o.x = (unsigned short)f2bf_bits(f.x);
    o.y = (unsigned short)f2bf_bits(f.y);
    o.z = (unsigned short)f2bf_bits(f.z);
    o.w = (unsigned short)f2bf_bits(f.w);
    *(ushort4*)(dst + i) = o;
}

// ---- K1: 32x64-tile gload_lds GEMM, dual-shape: C = exp(2*(X @ W^T)) --------
// Part A (blk<512):  X=qb[2048x512],  W=Wsb[512x512],  C=EA  [2048x512] fp32
// Part B (blk>=512): X=Whb[512x512],  W=eb[2048x512],  C=EBT [512][2048] bf16
__global__ __launch_bounds__(256) void gemm32x64_exp_dual(
    const unsigned short* __restrict__ Xa, const unsigned short* __restrict__ Wa,
    float* __restrict__ Ca,
    const unsigned short* __restrict__ Xb, const unsigned short* __restrict__ Wb_,
    unsigned short* __restrict__ Cbt)
{
    __shared__ unsigned short sA[32 * 64];   // 4 KB, linear (swizzled content)
    __shared__ unsigned short sB[64 * 64];   // 8 KB
    const int K = 512;
    int blk = blockIdx.x;
    bool isA = (blk < 512);
    const unsigned short* X; const unsigned short* W;
    int mt, nt, N;
    if (isA) { X = Xa; W = Wa; N = 512;  mt = blk >> 3; nt = blk & 7; }
    else { blk -= 512; X = Xb; W = Wb_; N = 2048; mt = blk >> 5; nt = blk & 31; }
    int row0 = mt * 32, col0 = nt * 64;
    int tid = threadIdx.x, lane = tid & 63, w = tid >> 6;
    int mw = (w & 1) * 16, nw = (w >> 1) * 32;
    int r = lane & 15;

    // staging: wave w stages A rows 8w..8w+7 (1 call) and B rows 16w..16w+15
    // (2 calls). lane l -> row +(l>>3), col chunk ((l&7)^(l>>3))*8 shorts.
    int lr  = lane >> 3;
    int csw = ((lane & 7) ^ lr) << 3;        // swizzled col (shorts)
    const unsigned short* gA  = X + (size_t)(row0 + 8 * w + lr) * K + csw;
    const unsigned short* gB0 = W + (size_t)(col0 + 16 * w + lr) * K + csw;
    const unsigned short* gB1 = W + (size_t)(col0 + 16 * w + 8 + lr) * K + csw;
    unsigned short* lA  = &sA[w * 512];
    unsigned short* lB0 = &sB[w * 1024];
    unsigned short* lB1 = &sB[w * 1024 + 512];

    // read offsets (bytes), loop-invariant
    int xr = (r & 7) << 4;
    int cq = (lane >> 4) << 4;               // 0,16,32,48
    const char* cA = (const char*)sA;
    const char* cB = (const char*)sB;
    int a0 = (mw + r) * 128 + (cq ^ xr);
    int a1 = (mw + r) * 128 + ((cq + 64) ^ xr);
    int b0 = (nw + r) * 128 + (cq ^ xr);
    int b1 = (nw + r) * 128 + ((cq + 64) ^ xr);

    floatx4 acc0 = {0,0,0,0}, acc1 = {0,0,0,0};
    gload16(gA, lA); gload16(gB0, lB0); gload16(gB1, lB1);   // stage kb=0

    for (int kb = 0; kb < 8; ++kb) {
        __syncthreads();                     // drains vmcnt -> tile ready
        bf16x8 af0 = *(const bf16x8*)(cA + a0);
        bf16x8 af1 = *(const bf16x8*)(cA + a1);
        bf16x8 b00 = *(const bf16x8*)(cB + b0);
        bf16x8 b10 = *(const bf16x8*)(cB + b0 + 2048);
        bf16x8 b01 = *(const bf16x8*)(cB + b1);
        bf16x8 b11 = *(const bf16x8*)(cB + b1 + 2048);
        acc0 = __builtin_amdgcn_mfma_f32_16x16x32_bf16(af0, b00, acc0, 0, 0, 0);
        acc1 = __builtin_amdgcn_mfma_f32_16x16x32_bf16(af0, b10, acc1, 0, 0, 0);
        acc0 = __builtin_amdgcn_mfma_f32_16x16x32_bf16(af1, b01, acc0, 0, 0, 0);
        acc1 = __builtin_amdgcn_mfma_f32_16x16x32_bf16(af1, b11, acc1, 0, 0, 0);
        if (kb < 7) {
            __syncthreads();                 // all waves done reading
            gA += 64; gB0 += 64; gB1 += 64;
            gload16(gA, lA); gload16(gB0, lB0); gload16(gB1, lB1);
        }
    }
    int rq = (lane >> 4) * 4;
    if (isA) {
        float* cp = Ca + (size_t)(row0 + mw + rq) * N + col0 + nw + r;
#pragma unroll
        for (int i = 0; i < 4; ++i) {
            cp[(size_t)i * N]      = fexp2x(acc0[i]);
            cp[(size_t)i * N + 16] = fexp2x(acc1[i]);
        }
    } else {
        unsigned short* cp = Cbt + (size_t)(row0 + mw + rq) * N + col0 + nw + r;
#pragma unroll
        for (int i = 0; i < 4; ++i) {
            cp[(size_t)i * N]      = (unsigned short)f2bf_bits(fexp2x(acc0[i]));
            cp[(size_t)i * N + 16] = (unsigned short)f2bf_bits(fexp2x(acc1[i]));
        }
    }
}

// ---- K2: energies. 1024 blocks = (b<<7)|(j<<6)|tq, 512 thr ------------------
// Block: batch b, t-rows tq*4..+3, s-group j (128 s). Early exit: j*128>=len.
// Wave w: h-slice [w*64,w*64+64); lane: s = j*128 + 2*lane + {0,1}.
// E(t,s) = sum_h wn_h/(1+EA*EB), wn=-2v. EBT is bf16: one u32 = 2 s-values
// (lo ushort = s even, hi = s odd; unpack lo=u<<16, hi=u&0xffff0000).
// 4 loads/4-h iter (half of v6); B/P state 8 u32 regs (v6: 16 floats).
__global__ __launch_bounds__(512) void energies_v11(
    const float* __restrict__ EA,            // [2048][512] e^{2*Ws_q} fp32
    const unsigned short* __restrict__ EBT,  // [512][2048] bf16 e^{2*Wh_e}^T
    const float* __restrict__ Vv,            // fp32 512
    const int* __restrict__ Len,
    float* __restrict__ E)                   // fp32 [2048][256]
{
    __shared__ float sA[TQ][516];            // 8.25 KB, uniform broadcast reads
    __shared__ float sWn[512];               // 2 KB  (-2*v)
    __shared__ __align__(16) float sRed[8][TQ][130];   // 16.6 KB

    int tid  = threadIdx.x;
    int lane = tid & 63;
    int w    = tid >> 6;
    int blk  = blockIdx.x;
    int b    = blk >> 7;
    int j    = (blk >> 6) & 1;
    int tq   = blk & 63;                   // low bits -> XCD balance
    int len  = Len[b];
    if (j * 128 >= len) return;            // block-uniform early exit
    int row0g = b * 256 + tq * TQ;

    {   // stage EA rows (4 x 512 fp32) and wn
        int t = tid >> 7, c = (tid & 127) * 4;
        *(float4*)&sA[t][c] = *(const float4*)(EA + (size_t)(row0g + t) * 512 + c);
        sWn[tid] = -2.0f * Vv[tid];
    }
    __syncthreads();

    int h0 = w * 64;
    float acc[TQ][2] = {{0.f}};
    const unsigned short* bt = EBT + (size_t)h0 * 2048 + b * 256 + j * 128 + 2 * lane;

    // software pipeline: prefetch B for hh=0 (4 h, u32 = 2 bf16 s-values)
    unsigned int B4[4], P4[4];
#pragma unroll
    for (int i = 0; i < 4; ++i) B4[i] = *(const unsigned int*)(bt + (size_t)i * 2048);
#pragma unroll
    for (int hh = 0; hh < 64; hh += 4) {
        if (hh + 4 < 64) {                 // prefetch next iteration's B
            const unsigned short* nb = bt + (size_t)(hh + 4) * 2048;
#pragma unroll
            for (int i = 0; i < 4; ++i) P4[i] = *(const unsigned int*)(nb + (size_t)i * 2048);
        }
        float bl[4], bh[4];                // unpack once, reuse across 4 t
#pragma unroll
        for (int i = 0; i < 4; ++i) {
            bl[i] = __uint_as_float(B4[i] << 16);
            bh[i] = __uint_as_float(B4[i] & 0xffff0000u);
        }
        float4 w4 = *(const float4*)&sWn[h0 + hh];            // LDS broadcast
#pragma unroll
        for (int t = 0; t < TQ; ++t) {
            float4 a4 = *(const float4*)&sA[t][h0 + hh];      // LDS broadcast
            {   // u = 0: s = 2*lane
                float d0 = fmaf(a4.x, bl[0], 1.0f);
                float d1 = fmaf(a4.y, bl[1], 1.0f);
                float d2 = fmaf(a4.z, bl[2], 1.0f);
                float d3 = fmaf(a4.w, bl[3], 1.0f);
                float num01 = fmaf(w4.x, d1, w4.y * d0);
                float num23 = fmaf(w4.z, d3, w4.w * d2);
                acc[t][0] = fmaf(num01, frcp(d0 * d1), acc[t][0]);
                acc[t][0] = fmaf(num23, frcp(d2 * d3), acc[t][0]);
            }
            {   // u = 1: s = 2*lane+1
                float d0 = fmaf(a4.x, bh[0], 1.0f);
                float d1 = fmaf(a4.y, bh[1], 1.0f);
                float d2 = fmaf(a4.z, bh[2], 1.0f);
                float d3 = fmaf(a4.w, bh[3], 1.0f);
                float num01 = fmaf(w4.x, d1, w4.y * d0);
                float num23 = fmaf(w4.z, d3, w4.w * d2);
                acc[t][1] = fmaf(num01, frcp(d0 * d1), acc[t][1]);
                acc[t][1] = fmaf(num23, frcp(d2 * d3), acc[t][1]);
            }
        }
#pragma unroll
        for (int i = 0; i < 4; ++i) B4[i] = P4[i];
    }

#pragma unroll
    for (int t = 0; t < TQ; ++t) {
        float2 av = {acc[t][0], acc[t][1]};
        *(float2*)&sRed[w][t][2 * lane] = av;   // s-pair layout (v7-verified)
    }
    __syncthreads();
    {
        int t = tid >> 7, s = tid & 127;   // 512 thr cover 4t x 128s
        float sum = 0.f;
#pragma unroll
        for (int ww = 0; ww < 8; ++ww) sum += sRed[ww][t][s];
        E[(size_t)(row0g + t) * 256 + j * 128 + s] = sum;
    }
}

// ---- K3: fused softmax + ctx GEMM. 256 blocks = (tg<<6)|(hq<<3)|b, 512 thr --
__global__ __launch_bounds__(512) void softmax_ctx_fused(
    const float* __restrict__ E,             // fp32 [2048][256]
    const unsigned short* __restrict__ Eb,   // bf16 8x256x512
    const int* __restrict__ Len,
    unsigned short* __restrict__ Ctx)        // bf16 2048x512
{
    __shared__ unsigned short EncT[64][264];
    __shared__ unsigned short sWb[64][264];
    int tid = threadIdx.x, lane = tid & 63, w = tid >> 6;
    int blk = blockIdx.x;
    int b = blk & 7, hq = (blk >> 3) & 7, tg = blk >> 6;
    int len = Len[b];

    {   // stage + transpose enc tile: thread (s, 32-h half)
        int s = tid >> 1, hg = (tid & 1) * 32;
        const ushort4* src = (const ushort4*)(Eb + (size_t)(b * 256 + s) * 512 + hq * 64 + hg);
#pragma unroll
        for (int k = 0; k < 8; ++k) {
            ushort4 u = src[k];
            EncT[hg + k * 4 + 0][s] = u.x;
            EncT[hg + k * 4 + 1][s] = u.y;
            EncT[hg + k * 4 + 2][s] = u.z;
            EncT[hg + k * 4 + 3][s] = u.w;
        }
    }
    // softmax: wave w owns rows w*8 .. w*8+7 of the 64-row tile
    for (int i = 0; i < 8; ++i) {
        int row = w * 8 + i;
        const float* erow = E + (size_t)(b * 256 + tg * 64 + row) * 256;
        float ev[4];
#pragma unroll
        for (int j = 0; j < 4; ++j) {
            int s = lane + 64 * j;
            ev[j] = (s < len) ? erow[s] : NEGBIG;
        }
        float m = fmaxf(fmaxf(ev[0], ev[1]), fmaxf(ev[2], ev[3]));
#pragma unroll
        for (int o = 1; o < 64; o <<= 1) m = fmaxf(m, __shfl_xor(m, o, 64));
        float wv[4], wsum = 0.f;
#pragma unroll
        for (int j = 0; j < 4; ++j) { wv[j] = fexp2((ev[j] - m) * LOG2E); wsum += wv[j]; }
#pragma unroll
        for (int o = 1; o < 64; o <<= 1) wsum += __shfl_xor(wsum, o, 64);
        float inv = frcp(wsum);
#pragma unroll
        for (int j = 0; j < 4; ++j)
            sWb[row][lane + 64 * j] = (unsigned short)f2bf_bits(wv[j] * inv);
    }
    __syncthreads();

    int mt = w & 3, npair = w >> 2;          // wave: 16 t x 32 h (2 n-tiles)
    int t0 = mt * 16;
    int r  = lane & 15, kq = (lane >> 4) * 8;
    int n0 = npair * 32 + r;
    floatx4 acc0 = {0.f,0.f,0.f,0.f}, acc1 = {0.f,0.f,0.f,0.f};
#pragma unroll
    for (int k = 0; k < 8; ++k) {
        bf16x8 a  = *(const bf16x8*)(&sWb[t0 + r][kq + 32 * k]);
        bf16x8 b0 = *(const bf16x8*)(&EncT[n0][kq + 32 * k]);
        bf16x8 b1 = *(const bf16x8*)(&EncT[n0 + 16][kq + 32 * k]);
        acc0 = __builtin_amdgcn_mfma_f32_16x16x32_bf16(a, b0, acc0, 0, 0, 0);
        acc1 = __builtin_amdgcn_mfma_f32_16x16x32_bf16(a, b1, acc1, 0, 0, 0);
    }
    int row0 = (lane >> 4) * 4;
    unsigned short* op = Ctx + (size_t)(b * 256 + tg * 64 + t0 + row0) * 512 + hq * 64 + npair * 32 + r;
#pragma unroll
    for (int i = 0; i < 4; ++i) {
        op[i * 512]      = (unsigned short)f2bf_bits(acc0[i]);
        op[i * 512 + 16] = (unsigned short)f2bf_bits(acc1[i]);
    }
}

// ---- K4: 32x64-tile gload_lds GEMM, concat-K: out = tanh([ctx|q] @ Wout^T) --
__global__ __launch_bounds__(256) void out_gemm32x64_tanh(
    const unsigned short* __restrict__ Ctx, const unsigned short* __restrict__ Q,
    const unsigned short* __restrict__ Wout, float* __restrict__ Out)
{
    __shared__ unsigned short sA[32 * 64];
    __shared__ unsigned short sB[64 * 64];
    const int N = 512, KW = 1024;
    int blk = blockIdx.x;
    int mt = blk >> 3, nt = blk & 7;
    int row0 = mt * 32, col0 = nt * 64;
    int tid = threadIdx.x, lane = tid & 63, w = tid >> 6;
    int mw = (w & 1) * 16, nw = (w >> 1) * 32;
    int r = lane & 15;

    int lr  = lane >> 3;
    int csw = ((lane & 7) ^ lr) << 3;
    const unsigned short* gactx = Ctx  + (size_t)(row0 + 8 * w + lr) * 512 + csw;
    const unsigned short* gaq   = Q    + (size_t)(row0 + 8 * w + lr) * 512 + csw;
    const unsigned short* gB0   = Wout + (size_t)(col0 + 16 * w + lr) * KW + csw;
    const unsigned short* gB1   = Wout + (size_t)(col0 + 16 * w + 8 + lr) * KW + csw;
    unsigned short* lA  = &sA[w * 512];
    unsigned short* lB0 = &sB[w * 1024];
    unsigned short* lB1 = &sB[w * 1024 + 512];

    int xr = (r & 7) << 4;
    int cq = (lane >> 4) << 4;
    const char* cA = (const char*)sA;
    const char* cB = (const char*)sB;
    int a0 = (mw + r) * 128 + (cq ^ xr);
    int a1 = (mw + r) * 128 + ((cq + 64) ^ xr);
    int b0 = (nw + r) * 128 + (cq ^ xr);
    int b1 = (nw + r) * 128 + ((cq + 64) ^ xr);

    floatx4 acc0 = {0,0,0,0}, acc1 = {0,0,0,0};
    gload16(gactx, lA); gload16(gB0, lB0); gload16(gB1, lB1);   // stage kb=0

    for (int kb = 0; kb < 16; ++kb) {
        __syncthreads();
        bf16x8 af0 = *(const bf16x8*)(cA + a0);
        bf16x8 af1 = *(const bf16x8*)(cA + a1);
        bf16x8 b00 = *(const bf16x8*)(cB + b0);
        bf16x8 b10 = *(const bf16x8*)(cB + b0 + 2048);
        bf16x8 b01 = *(const bf16x8*)(cB + b1);
        bf16x8 b11 = *(const bf16x8*)(cB + b1 + 2048);
        acc0 = __builtin_amdgcn_mfma_f32_16x16x32_bf16(af0, b00, acc0, 0, 0, 0);
        acc1 = __builtin_amdgcn_mfma_f32_16x16x32_bf16(af0, b10, acc1, 0, 0, 0);
        acc0 = __builtin_amdgcn_mfma_f32_16x16x32_bf16(af1, b01, acc0, 0, 0, 0);
        acc1 = __builtin_amdgcn_mfma_f32_16x16x32_bf16(af1, b11, acc1, 0, 0, 0);
        if (kb < 15) {
            __syncthreads();
            int kn = kb + 1;
            const unsigned short* ga = (kn < 8 ? gactx : gaq) + (kn & 7) * 64;
            gB0 += 64; gB1 += 64;
            gload16(ga, lA); gload16(gB0, lB0); gload16(gB1, lB1);
        }
    }
    int rq = (lane >> 4) * 4;
    float* op = Out + (size_t)(row0 + mw + rq) * N + col0 + nw + r;
#pragma unroll
    for (int i = 0; i < 4; ++i) {
        op[(size_t)i * N]      = ftanh(acc0[i]);
        op[(size_t)i * N + 16] = ftanh(acc1[i]);
    }
}

extern "C" void kernel_launch(void* const* d_in, const int* in_sizes, int n_in,
                              void* d_out, int out_size, void* d_ws, size_t ws_size,
                              hipStream_t stream)
{
    const float* query = (const float*)d_in[0]; // fp32 8x256x512
    const float* enc   = (const float*)d_in[1]; // fp32 8x256x512
    const int*   len   = (const int*)d_in[2];   // int32 8
    const float* Ws    = (const float*)d_in[3]; // fp32 512x512
    const float* Wh    = (const float*)d_in[4]; // fp32 512x512
    const float* v     = (const float*)d_in[5]; // fp32 512
    const float* Wout  = (const float*)d_in[6]; // fp32 512x1024
    float* out = (float*)d_out;                 // fp32 8x256x512

    // d_ws is 256 MiB; generous non-aliased layout (~16 MB used)
    float* EA   = (float*)d_ws;                                   // 4 MB [2048][512]
    float* E    = EA + 2048 * 512;                                // 2 MB [2048][256]
    unsigned short* EBTb = (unsigned short*)(E + 2048 * 256);     // 2 MB [512][2048] bf16
    unsigned short* qb  = EBTb + 512 * 2048;                      // 2 MB
    unsigned short* eb  = qb + 2048 * 512;                        // 2 MB
    unsigned short* Wsb = eb + 2048 * 512;                        // 0.5 MB
    unsigned short* Whb = Wsb + 512 * 512;                        // 0.5 MB
    unsigned short* Wob = Whb + 512 * 512;                        // 1 MB
    unsigned short* ctx = Wob + 512 * 1024;                       // 2 MB

    cast_all_bf16<<<3072, 256, 0, stream>>>(query, enc, Ws, Wh, Wout,
                                            qb, eb, Wsb, Whb, Wob);
    gemm32x64_exp_dual<<<1024, 256, 0, stream>>>(qb, Wsb, EA, Whb, eb, EBTb);
    energies_v11<<<1024, 512, 0, stream>>>(EA, EBTb, v, len, E);
    softmax_ctx_fused<<<256, 512, 0, stream>>>(E, eb, len, ctx);
    out_gemm32x64_tanh<<<512, 256, 0, stream>>>(ctx, qb, Wob, out);
}